// Round 10
// baseline (135.641 us; speedup 1.0000x reference)
//
#include <hip/hip_runtime.h>

// QuantumAttention: B=8, S=2048, E=8, H=2, D=4, NQ=8
//
// R1-R8: every scalar structure (LDS broadcast, readlane, s_load) plateaus at
// 30-46us, VALUBusy <=40% -- per-pair VALU issue (10 slots) + latency chains.
// R9: QK^T moves to the matrix pipe. S^T-tile = mfma_f32_16x16x32_f16 with
// A=K (m=j), B=Q (n=i), k=d (4 of 32 slots; waste irrelevant -- MFMA pipe
// ~1us total). C-layout (verified m89): lane(q=lane>>4, n=lane&15) reg r =
// S^T[j=4q+r][i=n]. exp + PV stay fp32 VALU: lane accumulates acc[i=n][d]
// over its j's (same i per lane -> NO cross-lane transpose); final 2x
// shfl_xor reduce. Only Q,K are f16 (score err ~2e-3); V/P/acc fp32.
// (R9 fix: cvt_pkrtz returns __fp16 ext_vector(2); memcpy bits.)
//
// Quantum circuit closed-form: c_w = cos(tok[w]+tok[w%4]);
// z[0]=c1..c7, z[q>=1]=c0..cq. Softmax one-pass; 0.5*log2(e) folded into Q.

#define SS 2048
#define EE 8

typedef __attribute__((ext_vector_type(8))) _Float16 f16x8;
typedef __attribute__((ext_vector_type(4))) float f32x4;

union FragU { int4 w; f16x8 v; };

__device__ __forceinline__ int pkh(float a, float b) {
    __fp16 __attribute__((ext_vector_type(2))) h = __builtin_amdgcn_cvt_pkrtz(a, b);
    int r; __builtin_memcpy(&r, &h, 4); return r;
}

// ---- prep: K A-frag image (f16, 512KB) + V fp32 buffer (512KB) ----
// Kimg entry gid = (bh*128 + tile)*16 + n : {f16 K[j][0],K[1],K[2],K[3], 0..0}
// Vbuf entry vg = bh*2048 + j : float4 V[j][0..3]
extern "C" __global__ __launch_bounds__(256)
void qa_prep(const float* __restrict__ x, const float* __restrict__ Wk,
             const float* __restrict__ Wv,
             int4* __restrict__ Kimg, float4* __restrict__ Vbuf) {
    const int gid = blockIdx.x * 256 + threadIdx.x;
    if (gid < 32768) {
        const int n = gid & 15, tile = (gid >> 4) & 127, bh = gid >> 11;
        const int h = bh & 1, b = bh >> 1;
        const int j = tile * 16 + n;
        const float* xp = x + ((size_t)(b * SS + j)) * EE;
        float xv[8];
        *(float4*)&xv[0] = *(const float4*)xp;
        *(float4*)&xv[4] = *(const float4*)(xp + 4);
        float kd[4];
        #pragma unroll
        for (int d = 0; d < 4; ++d) {
            float s = 0.f;
            #pragma unroll
            for (int e = 0; e < 8; ++e) s += xv[e] * Wk[(h * 4 + d) * EE + e];
            kd[d] = s;
        }
        Kimg[gid] = make_int4(pkh(kd[0], kd[1]), pkh(kd[2], kd[3]), 0, 0);
    } else {
        const int vg = gid - 32768;
        const int j = vg & 2047, bh = vg >> 11;
        const int h = bh & 1, b = bh >> 1;
        const float* xp = x + ((size_t)(b * SS + j)) * EE;
        float xv[8];
        *(float4*)&xv[0] = *(const float4*)xp;
        *(float4*)&xv[4] = *(const float4*)(xp + 4);
        float vd[4];
        #pragma unroll
        for (int d = 0; d < 4; ++d) {
            float s = 0.f;
            #pragma unroll
            for (int e = 0; e < 8; ++e) s += xv[e] * Wv[(h * 4 + d) * EE + e];
            vd[d] = s;
        }
        Vbuf[vg] = make_float4(vd[0], vd[1], vd[2], vd[3]);
    }
}

// ---- attention: 512 blocks (b<<6|h<<5|rt), 256 thr = 4 waves.
// wave owns Q-rows i0 = rt*64 + w*16 .. +15; loops 128 K-tiles of 16 j.
extern "C" __global__ __launch_bounds__(256)
void qa_attn_mf(const float* __restrict__ x, const float* __restrict__ Wq,
                const int4* __restrict__ Kimg, const float4* __restrict__ Vbuf,
                float* __restrict__ AO) {
    const int bid = blockIdx.x;
    const int rt = bid & 31, h = (bid >> 5) & 1, b = bid >> 6, bh = b * 2 + h;
    const int tid = threadIdx.x, lane = tid & 63, w = tid >> 6;
    const int q4 = lane >> 4, n = lane & 15;
    const int i0 = rt * 64 + w * 16;

    // Q B-frag: B[k=d][n=i], only k<4 (and only q4==0 k-slots) nonzero.
    FragU qf; qf.w = make_int4(0, 0, 0, 0);
    {
        const float* xp = x + ((size_t)(b * SS + i0 + n)) * EE;
        float xv[8];
        *(float4*)&xv[0] = *(const float4*)xp;
        *(float4*)&xv[4] = *(const float4*)(xp + 4);
        float qd[4];
        #pragma unroll
        for (int d = 0; d < 4; ++d) {
            float s = 0.f;
            #pragma unroll
            for (int e = 0; e < 8; ++e) s += xv[e] * Wq[(h * 4 + d) * EE + e];
            qd[d] = s * 0.72134752044f;   // 0.5 * log2(e) -> bare exp2
        }
        if (q4 == 0) qf.w = make_int4(pkh(qd[0], qd[1]), pkh(qd[2], qd[3]), 0, 0);
    }

    // K entry address uses only n -> all 4 quads read the SAME 16B (broadcast);
    // quads 1-3 see K data in k-slots >=8 where Q-frag is zero -> harmless.
    const int4*   Kp = Kimg + bh * 2048 + n;
    const float4* Vp = Vbuf + bh * 2048 + q4 * 4;

    float den = 0.f, ac0 = 0.f, ac1 = 0.f, ac2 = 0.f, ac3 = 0.f;
    #pragma unroll 4
    for (int t = 0; t < 128; ++t) {
        FragU kf; kf.w = Kp[t * 16];
        f32x4 S = __builtin_amdgcn_mfma_f32_16x16x32_f16(
            kf.v, qf.v, (f32x4){0.f, 0.f, 0.f, 0.f}, 0, 0, 0);
        const float4 v0 = Vp[t * 16 + 0];
        const float4 v1 = Vp[t * 16 + 1];
        const float4 v2 = Vp[t * 16 + 2];
        const float4 v3 = Vp[t * 16 + 3];
        const float e0 = __builtin_amdgcn_exp2f(S[0]);
        const float e1 = __builtin_amdgcn_exp2f(S[1]);
        const float e2 = __builtin_amdgcn_exp2f(S[2]);
        const float e3 = __builtin_amdgcn_exp2f(S[3]);
        den += (e0 + e1) + (e2 + e3);
        // per-tile sums, then one carried add per accumulator (short chains)
        ac0 += fmaf(e0, v0.x, fmaf(e1, v1.x, fmaf(e2, v2.x, e3 * v3.x)));
        ac1 += fmaf(e0, v0.y, fmaf(e1, v1.y, fmaf(e2, v2.y, e3 * v3.y)));
        ac2 += fmaf(e0, v0.z, fmaf(e1, v1.z, fmaf(e2, v2.z, e3 * v3.z)));
        ac3 += fmaf(e0, v0.w, fmaf(e1, v1.w, fmaf(e2, v2.w, e3 * v3.w)));
    }

    // reduce across the 4 quads (j-subsets); lane (q,n) -> full row i=n
    den += __shfl_xor(den, 16); den += __shfl_xor(den, 32);
    ac0 += __shfl_xor(ac0, 16); ac0 += __shfl_xor(ac0, 32);
    ac1 += __shfl_xor(ac1, 16); ac1 += __shfl_xor(ac1, 32);
    ac2 += __shfl_xor(ac2, 16); ac2 += __shfl_xor(ac2, 32);
    ac3 += __shfl_xor(ac3, 16); ac3 += __shfl_xor(ac3, 32);

    if (lane < 16) {
        const float inv = 1.f / den;
        *(float4*)(AO + ((size_t)((b * SS + i0 + n) * 2 + h)) * 4) =
            make_float4(ac0 * inv, ac1 * inv, ac2 * inv, ac3 * inv);
    }
}

// ---- per-token closed-form quantum measurement + Wo ----
extern "C" __global__ __launch_bounds__(256)
void qa_quantum(const float* __restrict__ AO, const float* __restrict__ Wo,
                float* __restrict__ out) {
    __shared__ float wo[64];
    const int tid = threadIdx.x;
    if (tid < 64) wo[tid] = Wo[tid];
    __syncthreads();

    const int g = blockIdx.x * 256 + tid;   // token 0..16383
    const float* tp = AO + (size_t)g * 8;
    float4 t0 = *(const float4*)tp;
    float4 t1 = *(const float4*)(tp + 4);
    float tok[8] = {t0.x, t0.y, t0.z, t0.w, t1.x, t1.y, t1.z, t1.w};

    float c[8];
    #pragma unroll
    for (int ww = 0; ww < 8; ++ww) c[ww] = __cosf(tok[ww] + tok[ww & 3]);

    float z[8];
    float p = 1.f;
    #pragma unroll
    for (int qq = 1; qq < 8; ++qq) { p *= c[qq]; z[qq] = p; }
    z[0] = p;                       // c1..c7
    #pragma unroll
    for (int qq = 1; qq < 8; ++qq) z[qq] *= c[0];   // c0..cq

    float y[8];
    #pragma unroll
    for (int f = 0; f < 8; ++f) {
        float s = 0.f;
        #pragma unroll
        for (int qq = 0; qq < 8; ++qq) s += z[qq] * wo[f * 8 + qq];
        y[f] = s;
    }
    float* op = out + (size_t)g * 8;
    *(float4*)op       = make_float4(y[0], y[1], y[2], y[3]);
    *(float4*)(op + 4) = make_float4(y[4], y[5], y[6], y[7]);
}

extern "C" void kernel_launch(void* const* d_in, const int* in_sizes, int n_in,
                              void* d_out, int out_size, void* d_ws, size_t ws_size,
                              hipStream_t stream) {
    const float* x  = (const float*)d_in[0];
    const float* Wq = (const float*)d_in[1];
    const float* Wk = (const float*)d_in[2];
    const float* Wv = (const float*)d_in[3];
    const float* Wo = (const float*)d_in[4];
    float* out = (float*)d_out;

    int4*   Kimg = (int4*)d_ws;                            // 512 KB
    float4* Vbuf = (float4*)((char*)d_ws + (512 << 10));   // 512 KB
    float*  AO   = (float*)((char*)d_ws + (1 << 20));      // 512 KB

    qa_prep<<<dim3(256), dim3(256), 0, stream>>>(x, Wk, Wv, Kimg, Vbuf);
    qa_attn_mf<<<dim3(512), dim3(256), 0, stream>>>(x, Wq, Kimg, Vbuf, AO);
    qa_quantum<<<dim3(64), dim3(256), 0, stream>>>(AO, Wo, out);
}